// Round 8
// baseline (2652.996 us; speedup 1.0000x reference)
//
#include <hip/hip_runtime.h>
#include <cstdint>

#define N 8192
#define NT 128      // 64-col chunks per row (N/64)
typedef unsigned long long u64;
typedef unsigned int u32;

// ---------------------------------------------------------------------------
// K1: rank by counting, keys recomputed inline from scores (descending score,
// stable ascending index). Partial counts per y-slab -> rankpart[8][N].
// ---------------------------------------------------------------------------
__global__ __launch_bounds__(256) void k_rank(const float* __restrict__ scores,
                                              int* __restrict__ rankpart) {
  __shared__ u64 tile[1024];
  int e = blockIdx.x * 256 + threadIdx.x;
  int j0 = blockIdx.y * 1024;
  for (int t = threadIdx.x; t < 1024; t += 256) {
    int j = j0 + t;
    tile[t] = ((u64)__float_as_uint(scores[j]) << 32) | (unsigned)(0xFFFFFFFFu - (unsigned)j);
  }
  __syncthreads();
  u64 ke = ((u64)__float_as_uint(scores[e]) << 32) | (unsigned)(0xFFFFFFFFu - (unsigned)e);
  int c = 0;
#pragma unroll 8
  for (int k = 0; k < 1024; ++k) c += (tile[k] > ke) ? 1 : 0;
  rankpart[blockIdx.y * N + e] = c;
}

// ---------------------------------------------------------------------------
// K2: sum rank partials + scatter into sorted SoA + init aux.
// ---------------------------------------------------------------------------
__global__ __launch_bounds__(256) void k_scatter(const float* __restrict__ boxes,
                                                 const float* __restrict__ scores,
                                                 const int* __restrict__ rankpart,
                                                 float* __restrict__ bx1s, float* __restrict__ by1s,
                                                 float* __restrict__ bx2s, float* __restrict__ by2s,
                                                 float* __restrict__ ss, float* __restrict__ areas,
                                                 int* __restrict__ cnt,
                                                 float* __restrict__ prob,
                                                 u64* __restrict__ pk) {
#pragma clang fp contract(off)
  int i = blockIdx.x * 256 + threadIdx.x;
  if (i >= N) return;
  int r = 0;
#pragma unroll
  for (int q = 0; q < 8; ++q) r += rankpart[q * N + i];
  float x1 = fminf(fmaxf(boxes[i * 4 + 0], 0.0f), 1920.0f);
  float y1 = fminf(fmaxf(boxes[i * 4 + 1], 0.0f), 1080.0f);
  float x2 = fminf(fmaxf(boxes[i * 4 + 2], 0.0f), 1920.0f);
  float y2 = fminf(fmaxf(boxes[i * 4 + 3], 0.0f), 1080.0f);
  bx1s[r] = x1; by1s[r] = y1; bx2s[r] = x2; by2s[r] = y2;
  ss[r] = scores[i];
  areas[r] = (x2 - x1 + 1.0f) * (y2 - y1 + 1.0f);
  cnt[i] = 0;
  prob[i] = 0.0f;
  pk[i] = 0ull;
}

// ---------------------------------------------------------------------------
// K3: adjacency, SYMMETRIC lower-triangle blocks + ballot transpose.
// Band trick (verified absmax 0.0): iou>0.5 <=> 2*inter>uni whenever
// |2*inter-uni| > 1e-6*uni; only in-band lanes take the exact IEEE divide.
// fp contract OFF everywhere; matrix float-exact symmetric.
// ---------------------------------------------------------------------------
__global__ __launch_bounds__(64) void k_adj(const float* __restrict__ bx1s, const float* __restrict__ by1s,
                                            const float* __restrict__ bx2s, const float* __restrict__ by2s,
                                            const float* __restrict__ areas,
                                            u64* __restrict__ mtile,
                                            u64* __restrict__ mrow) {
#pragma clang fp contract(off)
  __shared__ float jx1[64], jy1[64], jx2[64], jy2[64], ja[64];
  int p = blockIdx.x;
  int gy = (int)((sqrtf(8.0f * (float)p + 1.0f) - 1.0f) * 0.5f);
  while ((gy + 1) * (gy + 2) / 2 <= p) ++gy;
  while (gy * (gy + 1) / 2 > p) --gy;
  int gx = p - gy * (gy + 1) / 2;

  int l = threadIdx.x;
  int j = gx * 64 + l;
  jx1[l] = bx1s[j]; jy1[l] = by1s[j]; jx2[l] = bx2s[j]; jy2[l] = by2s[j]; ja[l] = areas[j];
  __syncthreads();
  int i = gy * 64 + l;
  float x1 = bx1s[i], y1 = by1s[i], x2 = bx2s[i], y2 = by2s[i], ai = areas[i];
  u64 bits = 0;
#pragma unroll 4
  for (int jj = 0; jj < 64; ++jj) {
    float ix1 = fmaxf(x1, jx1[jj]);
    float iy1 = fmaxf(y1, jy1[jj]);
    float ix2 = fminf(x2, jx2[jj]);
    float iy2 = fminf(y2, jy2[jj]);
    float iw = fmaxf(ix2 - ix1 + 1.0f, 0.0f);
    float ih = fmaxf(iy2 - iy1 + 1.0f, 0.0f);
    float inter = iw * ih;
    float uni = (ai + ja[jj]) - inter;   // uni > 0 always (areas >= 1)
    float t = inter + inter;             // exact (x2)
    bool gt = t > uni;
    bool amb = fabsf(t - uni) <= 1e-6f * uni;
    if (__ballot(amb) != 0ull) {         // ~never taken
      float iou = inter / uni;           // exact IEEE div, matches numpy
      if (amb) gt = iou > 0.5f;
    }
    bits |= ((u64)gt) << jj;
  }
  mtile[((size_t)gy * NT + gx) * 64 + l] = bits;
  mrow[(size_t)i * NT + gx] = bits;
  if (gx != gy) {
    u64 tb = 0;
#pragma unroll 8
    for (int c = 0; c < 64; ++c) {
      u64 wb = __ballot((bits >> c) & 1ull);
      tb = (l == c) ? wb : tb;
    }
    mtile[((size_t)gx * NT + gy) * 64 + l] = tb;
    mrow[(size_t)(gx * 64 + l) * NT + gy] = tb;
  }
}

// ---------------------------------------------------------------------------
// K4: EXACT single-sweep greedy classification, ONE wave, dual form.
//
// Round-7 A/B falsified the clobber theory: hand-pinned asm pipelines (r3/5/7)
// all serialize at ~650cy/candidate regardless of structure, and VGPR=84
// shows the 32 buffers were never register-resident. Meanwhile the ORIGINAL
// k_fix structure -- plain C loads, 8-deep runtime-indexed ring (scratch ok),
// ballot head-test -- MEASURED ~33cy/element (112us @ ~8200 elems, r1). The
// compiler pipelines that form correctly because IT owns the loads.
//
// Hybrid: keep the per-512-group candidate extraction (twice-verified exact;
// cuts work 8192 -> ~2750 rows) feeding a verbatim old-k_fix ring loop.
// D starts EMPTY and fills ascending, so the old below-mask is unnecessary:
//   hit = (row & D) != 0    (D = heads so far, all < j at j's turn)
//   head <=> ballot(hit)==0 (uniform)
// On head: D |= own bit; R |= row (suppressed bitmap, drives extraction).
// Extraction soundness: R only grows; filtered elements are suppressed for
// good. In-group suppressions are caught by the exact ballot test. Ascending
// production order => induction invariant holds. Exact (absmax 0.0 in r2-7
// variants of the same invariant).
// ---------------------------------------------------------------------------
__global__ __launch_bounds__(64, 1) void k_sweep(const u64* __restrict__ mrow,
                                                 u64* __restrict__ D) {
  __shared__ int ulist[512];
  int l = threadIdx.x;
  u64 R0 = 0, R1 = 0;   // suppressed bitmap: lane l owns u64 words 2l, 2l+1
  u64 D0 = 0, D1 = 0;   // head bitmap

  for (int g = 0; g < 16; ++g) {
    // ---- extraction: candidates = unsuppressed bits of group g
    //      (u64 words 8g..8g+7 live in lanes 4g..4g+3)
    bool in_ = ((l >> 2) == g);
    u64 c0 = in_ ? ~R0 : 0ull;
    u64 c1 = in_ ? ~R1 : 0ull;
    int cnt = __popcll(c0) + __popcll(c1);
    int pre = cnt;
#pragma unroll
    for (int d = 1; d < 64; d <<= 1) {
      int v = __shfl_up(pre, d);
      if (l >= d) pre += v;
    }
    int Mg = __shfl(pre, 63);
    int off = pre - cnt;
    int jb = l * 128;                   // element index of word 2l, bit 0
    while (c0) { int b = __builtin_ctzll(c0); c0 &= c0 - 1; ulist[off++] = jb + b; }
    while (c1) { int b = __builtin_ctzll(c1); c1 &= c1 - 1; ulist[off++] = jb + 64 + b; }
    __syncthreads();
    if (Mg == 0) continue;

    // ---- old-k_fix ring: 8-deep prefetch, plain C loads, index-clamped
    ulong2 ring[8];
    int pj[8];
#pragma unroll
    for (int q = 0; q < 8; ++q) {
      int j = ulist[q < Mg ? q : Mg - 1];
      pj[q] = j;
      ring[q] = *(const ulong2*)&mrow[(size_t)j * NT + 2 * l];
    }
    for (int m = 0; m < Mg; ++m) {
      int slot = m & 7;
      int j = pj[slot];
      ulong2 rv = ring[slot];
      bool hit = ((rv.x & D0) | (rv.y & D1)) != 0ull;
      bool head = (__ballot(hit) == 0ull);           // uniform
      u64 hm = head ? ~0ull : 0ull;                  // branchless (old style)
      u64 bset = 1ull << (j & 63);
      int jw = j >> 6;                               // uniform
      D0 |= ((jw == 2 * l) ? bset : 0ull) & hm;
      D1 |= ((jw == 2 * l + 1) ? bset : 0ull) & hm;
      R0 |= rv.x & hm;
      R1 |= rv.y & hm;
      int nm = m + 8;
      int j2 = ulist[nm < Mg ? nm : Mg - 1];
      pj[slot] = j2;
      ring[slot] = *(const ulong2*)&mrow[(size_t)j2 * NT + 2 * l];
    }
    __syncthreads();   // ulist reused next group
  }

  D[2 * l] = D0;
  D[2 * l + 1] = D1;
}

// ---------------------------------------------------------------------------
// K5: parallel cluster assignment + segment atomics. cluster[j] = first head
// adjacent to j (head index provably <= j) -> scan only tiles k <= gy.
// Fused "first index at cluster-max y2" via ONE packed u64 atomicMax:
// (y2_bits << 32) | ~j  -- y2 >= 0 so uint order == float order; tie -> min j.
// ---------------------------------------------------------------------------
__global__ __launch_bounds__(256) void k_cluster(const u64* __restrict__ mtile,
                                                 const u64* __restrict__ D,
                                                 const float* __restrict__ ss,
                                                 const float* __restrict__ by2s,
                                                 int* __restrict__ cluster,
                                                 int* __restrict__ cnt,
                                                 float* __restrict__ prob,
                                                 u64* __restrict__ pk) {
  __shared__ u64 hlds[NT];
  __shared__ int red[4][64];
  int gy = blockIdx.x;
  if (threadIdx.x < NT) hlds[threadIdx.x] = D[threadIdx.x];
  __syncthreads();
  int w = threadIdx.x >> 6, r = threadIdx.x & 63;
  int best = 0x7fffffff;
  for (int k = w; k <= gy; k += 4) {      // per-group candidates ascend with k
    u64 v = mtile[((size_t)gy * NT + k) * 64 + r] & hlds[k];
    if (v) { best = k * 64 + __builtin_ctzll(v); break; }
  }
  red[w][r] = best;
  __syncthreads();
  if (w == 0) {
    int b = min(min(red[0][r], red[1][r]), min(red[2][r], red[3][r]));
    int j = gy * 64 + r;
    cluster[j] = b;
    atomicAdd(&cnt[b], 1);
    atomicAdd(&prob[b], ss[j]);
    atomicMax((unsigned long long*)&pk[b],
              ((u64)__float_as_uint(by2s[j]) << 32) | (u64)(0xFFFFFFFFu - (unsigned)j));
  }
}

// ---------------------------------------------------------------------------
// K6: outputs. out[j][0..4] then keep[j] appended (floats 0/1).
// first index recovered from packed atomicMax: ~low32(pk).
// ---------------------------------------------------------------------------
__global__ __launch_bounds__(256) void k_out(const int* __restrict__ cluster,
                                             const float* __restrict__ bx1s, const float* __restrict__ by1s,
                                             const float* __restrict__ bx2s, const float* __restrict__ by2s,
                                             const int* __restrict__ cnt,
                                             const float* __restrict__ prob,
                                             const u64* __restrict__ pk,
                                             const int* __restrict__ num_models,
                                             float* __restrict__ out) {
  int j = blockIdx.x * 256 + threadIdx.x;
  if (j >= N) return;
  int c = cluster[j];
  int nm = num_models[0];
  bool valid = (float)cnt[c] >= (float)nm / 3.0f;
  unsigned fj = 0xFFFFFFFFu - (unsigned)(pk[c] & 0xFFFFFFFFull);
  bool keep = (fj == (unsigned)j) && valid;
  float o0 = 0.f, o1 = 0.f, o2 = 0.f, o3 = 0.f, o4 = 0.f;
  if (keep) {
    o0 = bx1s[j]; o1 = by1s[j]; o2 = bx2s[j]; o3 = by2s[j];
    o4 = prob[c] / (float)nm;
  }
  out[j * 5 + 0] = o0;
  out[j * 5 + 1] = o1;
  out[j * 5 + 2] = o2;
  out[j * 5 + 3] = o3;
  out[j * 5 + 4] = o4;
  out[N * 5 + j] = keep ? 1.0f : 0.0f;
}

// ---------------------------------------------------------------------------
extern "C" void kernel_launch(void* const* d_in, const int* in_sizes, int n_in,
                              void* d_out, int out_size, void* d_ws, size_t ws_size,
                              hipStream_t stream) {
  const float* boxes = (const float*)d_in[0];
  const float* scores = (const float*)d_in[1];
  const int* num_models = (const int*)d_in[2];
  float* out = (float*)d_out;

  char* p = (char*)d_ws;
  auto take = [&](size_t bytes) {
    char* r = p;
    p += (bytes + 255) & ~(size_t)255;
    return r;
  };
  int* rankpart = (int*)take((size_t)8 * N * 4);
  float* bx1s = (float*)take((size_t)N * 4);
  float* by1s = (float*)take((size_t)N * 4);
  float* bx2s = (float*)take((size_t)N * 4);
  float* by2s = (float*)take((size_t)N * 4);
  float* ss   = (float*)take((size_t)N * 4);
  float* areas= (float*)take((size_t)N * 4);
  int* cluster= (int*)take((size_t)N * 4);
  int* cnt    = (int*)take((size_t)N * 4);
  float* prob = (float*)take((size_t)N * 4);
  u64* pk     = (u64*)take((size_t)N * 8);            // packed (y2max, ~first)
  u64* D      = (u64*)take((size_t)NT * 8);           // head bitmap
  u64* mtile  = (u64*)take((size_t)NT * NT * 64 * 8); // 8 MiB tiled adjacency
  u64* mrow   = (u64*)take((size_t)N * NT * 8);       // 8 MiB row-major adjacency

  k_rank<<<dim3(N / 256, 8), 256, 0, stream>>>(scores, rankpart);
  k_scatter<<<N / 256, 256, 0, stream>>>(boxes, scores, rankpart,
                                         bx1s, by1s, bx2s, by2s, ss, areas,
                                         cnt, prob, pk);
  k_adj<<<NT * (NT + 1) / 2, 64, 0, stream>>>(bx1s, by1s, bx2s, by2s, areas, mtile, mrow);
  k_sweep<<<1, 64, 0, stream>>>(mrow, D);
  k_cluster<<<NT, 256, 0, stream>>>(mtile, D, ss, by2s, cluster, cnt, prob, pk);
  k_out<<<N / 256, 256, 0, stream>>>(cluster, bx1s, by1s, bx2s, by2s, cnt, prob, pk, num_models, out);
}

// Round 9
// 1035.375 us; speedup vs baseline: 2.5624x; 2.5624x over previous
//
#include <hip/hip_runtime.h>
#include <cstdint>

#define N 8192
#define NT 128      // 64-col chunks per row (N/64)
typedef unsigned long long u64;
typedef unsigned int u32;

// ---------------------------------------------------------------------------
// K1: rank by counting, keys recomputed inline from scores (descending score,
// stable ascending index). Partial counts per y-slab -> rankpart[8][N].
// ---------------------------------------------------------------------------
__global__ __launch_bounds__(256) void k_rank(const float* __restrict__ scores,
                                              int* __restrict__ rankpart) {
  __shared__ u64 tile[1024];
  int e = blockIdx.x * 256 + threadIdx.x;
  int j0 = blockIdx.y * 1024;
  for (int t = threadIdx.x; t < 1024; t += 256) {
    int j = j0 + t;
    tile[t] = ((u64)__float_as_uint(scores[j]) << 32) | (unsigned)(0xFFFFFFFFu - (unsigned)j);
  }
  __syncthreads();
  u64 ke = ((u64)__float_as_uint(scores[e]) << 32) | (unsigned)(0xFFFFFFFFu - (unsigned)e);
  int c = 0;
#pragma unroll 8
  for (int k = 0; k < 1024; ++k) c += (tile[k] > ke) ? 1 : 0;
  rankpart[blockIdx.y * N + e] = c;
}

// ---------------------------------------------------------------------------
// K2: sum rank partials + scatter into sorted SoA + init aux.
// ---------------------------------------------------------------------------
__global__ __launch_bounds__(256) void k_scatter(const float* __restrict__ boxes,
                                                 const float* __restrict__ scores,
                                                 const int* __restrict__ rankpart,
                                                 float* __restrict__ bx1s, float* __restrict__ by1s,
                                                 float* __restrict__ bx2s, float* __restrict__ by2s,
                                                 float* __restrict__ ss, float* __restrict__ areas,
                                                 int* __restrict__ cnt,
                                                 float* __restrict__ prob,
                                                 u64* __restrict__ pk) {
#pragma clang fp contract(off)
  int i = blockIdx.x * 256 + threadIdx.x;
  if (i >= N) return;
  int r = 0;
#pragma unroll
  for (int q = 0; q < 8; ++q) r += rankpart[q * N + i];
  float x1 = fminf(fmaxf(boxes[i * 4 + 0], 0.0f), 1920.0f);
  float y1 = fminf(fmaxf(boxes[i * 4 + 1], 0.0f), 1080.0f);
  float x2 = fminf(fmaxf(boxes[i * 4 + 2], 0.0f), 1920.0f);
  float y2 = fminf(fmaxf(boxes[i * 4 + 3], 0.0f), 1080.0f);
  bx1s[r] = x1; by1s[r] = y1; bx2s[r] = x2; by2s[r] = y2;
  ss[r] = scores[i];
  areas[r] = (x2 - x1 + 1.0f) * (y2 - y1 + 1.0f);
  cnt[i] = 0;
  prob[i] = 0.0f;
  pk[i] = 0ull;
}

// ---------------------------------------------------------------------------
// K3: adjacency, SYMMETRIC lower-triangle blocks + ballot transpose.
// Band trick (verified absmax 0.0): iou>0.5 <=> 2*inter>uni whenever
// |2*inter-uni| > 1e-6*uni; only in-band lanes take the exact IEEE divide.
// fp contract OFF everywhere; matrix float-exact symmetric.
// ---------------------------------------------------------------------------
__global__ __launch_bounds__(64) void k_adj(const float* __restrict__ bx1s, const float* __restrict__ by1s,
                                            const float* __restrict__ bx2s, const float* __restrict__ by2s,
                                            const float* __restrict__ areas,
                                            u64* __restrict__ mtile,
                                            u64* __restrict__ mrow) {
#pragma clang fp contract(off)
  __shared__ float jx1[64], jy1[64], jx2[64], jy2[64], ja[64];
  int p = blockIdx.x;
  int gy = (int)((sqrtf(8.0f * (float)p + 1.0f) - 1.0f) * 0.5f);
  while ((gy + 1) * (gy + 2) / 2 <= p) ++gy;
  while (gy * (gy + 1) / 2 > p) --gy;
  int gx = p - gy * (gy + 1) / 2;

  int l = threadIdx.x;
  int j = gx * 64 + l;
  jx1[l] = bx1s[j]; jy1[l] = by1s[j]; jx2[l] = bx2s[j]; jy2[l] = by2s[j]; ja[l] = areas[j];
  __syncthreads();
  int i = gy * 64 + l;
  float x1 = bx1s[i], y1 = by1s[i], x2 = bx2s[i], y2 = by2s[i], ai = areas[i];
  u64 bits = 0;
#pragma unroll 4
  for (int jj = 0; jj < 64; ++jj) {
    float ix1 = fmaxf(x1, jx1[jj]);
    float iy1 = fmaxf(y1, jy1[jj]);
    float ix2 = fminf(x2, jx2[jj]);
    float iy2 = fminf(y2, jy2[jj]);
    float iw = fmaxf(ix2 - ix1 + 1.0f, 0.0f);
    float ih = fmaxf(iy2 - iy1 + 1.0f, 0.0f);
    float inter = iw * ih;
    float uni = (ai + ja[jj]) - inter;   // uni > 0 always (areas >= 1)
    float t = inter + inter;             // exact (x2)
    bool gt = t > uni;
    bool amb = fabsf(t - uni) <= 1e-6f * uni;
    if (__ballot(amb) != 0ull) {         // ~never taken
      float iou = inter / uni;           // exact IEEE div, matches numpy
      if (amb) gt = iou > 0.5f;
    }
    bits |= ((u64)gt) << jj;
  }
  mtile[((size_t)gy * NT + gx) * 64 + l] = bits;
  mrow[(size_t)i * NT + gx] = bits;
  if (gx != gy) {
    u64 tb = 0;
#pragma unroll 8
    for (int c = 0; c < 64; ++c) {
      u64 wb = __ballot((bits >> c) & 1ull);
      tb = (l == c) ? wb : tb;
    }
    mtile[((size_t)gx * NT + gy) * 64 + l] = tb;
    mrow[(size_t)(gx * 64 + l) * NT + gy] = tb;
  }
}

// ---------------------------------------------------------------------------
// K4: EXACT single-sweep greedy classification, ONE wave, dual form.
//
// Round-8 failure: the runtime-indexed ring (ring[m&7]) went to SCRATCH in
// this loop-nest context (VGPR=28, 945cy/elem) even though the identical
// pattern was register-resident in round-1's standalone k_fix (VGPR=88,
// 33cy/elem) -- the unroll heuristic that rotated it is context-dependent.
// Rule #20 enforced BY CONSTRUCTION now: ZERO arrays, 8 NAMED (j,r) scalar
// pairs, steady-state loop hand-unrolled x8 so every access is static.
// Loads stay PLAIN C -- the compiler owns them and inserts correct in-order
// vmcnt waits 8-deep (the exact mechanism behind round-1's 33cy/elem).
//
// Algorithm (exact, absmax 0.0 in r2-r8 variants): per 512-group, extract
// unsuppressed bits of R into ulist (wave prefix-sum + scatter; sound filter
// since R only grows); process candidates ascending with ballot head-test
//   head <=> ballot((row & D) != 0) == 0   (D = heads so far, all < j)
// On head: D |= own bit, R |= row. In-group suppressions caught by the exact
// test; ascending order maintains the induction invariant.
// ---------------------------------------------------------------------------
__global__ __launch_bounds__(64, 1) void k_sweep(const u64* __restrict__ mrow,
                                                 u64* __restrict__ D) {
  __shared__ int ulist[512 + 16];
  int l = threadIdx.x;
  u64 R0 = 0, R1 = 0;   // suppressed bitmap: lane l owns u64 words 2l, 2l+1
  u64 D0 = 0, D1 = 0;   // head bitmap

  for (int g = 0; g < 16; ++g) {
    // ---- extraction: candidates = unsuppressed bits of group g
    //      (u64 words 8g..8g+7 live in lanes 4g..4g+3)
    bool in_ = ((l >> 2) == g);
    u64 c0 = in_ ? ~R0 : 0ull;
    u64 c1 = in_ ? ~R1 : 0ull;
    int cnt = __popcll(c0) + __popcll(c1);
    int pre = cnt;
#pragma unroll
    for (int d = 1; d < 64; d <<= 1) {
      int v = __shfl_up(pre, d);
      if (l >= d) pre += v;
    }
    int Mg = __shfl(pre, 63);
    int off = pre - cnt;
    if (l < 16) ulist[Mg + l] = 0;      // pads: valid row 0, never processed
    int jb = l * 128;                   // element index of word 2l, bit 0
    while (c0) { int b = __builtin_ctzll(c0); c0 &= c0 - 1; ulist[off++] = jb + b; }
    while (c1) { int b = __builtin_ctzll(c1); c1 &= c1 - 1; ulist[off++] = jb + 64 + b; }
    __syncthreads();
    if (Mg == 0) continue;

    // ---- 8-deep software pipeline, NAMED scalars only (no arrays)
    int j0, j1, j2, j3, j4, j5, j6, j7;
    ulong2 r0, r1, r2, r3, r4, r5, r6, r7;
#define LOADI(jv, rv, idx) { jv = ulist[idx];                                 \
    rv = *(const ulong2*)&mrow[(size_t)jv * NT + 2 * l]; }
    LOADI(j0, r0, 0) LOADI(j1, r1, 1) LOADI(j2, r2, 2) LOADI(j3, r3, 3)
    LOADI(j4, r4, 4) LOADI(j5, r5, 5) LOADI(j6, r6, 6) LOADI(j7, r7, 7)

#define STEP(jv, rv) {                                                        \
    bool hit = ((rv.x & D0) | (rv.y & D1)) != 0ull;                           \
    u64 hm = (__ballot(hit) == 0ull) ? ~0ull : 0ull;   /* uniform */          \
    u64 bset = 1ull << (jv & 63);                                             \
    int jw = jv >> 6;                                  /* uniform */          \
    D0 |= ((jw == 2 * l) ? bset : 0ull) & hm;                                 \
    D1 |= ((jw == 2 * l + 1) ? bset : 0ull) & hm;                             \
    R0 |= rv.x & hm;                                                          \
    R1 |= rv.y & hm;                                                          \
    LOADI(jv, rv, m + 8)                                                      \
    ++m; }

    int m = 0;
    while (true) {
      STEP(j0, r0) if (m >= Mg) break;
      STEP(j1, r1) if (m >= Mg) break;
      STEP(j2, r2) if (m >= Mg) break;
      STEP(j3, r3) if (m >= Mg) break;
      STEP(j4, r4) if (m >= Mg) break;
      STEP(j5, r5) if (m >= Mg) break;
      STEP(j6, r6) if (m >= Mg) break;
      STEP(j7, r7) if (m >= Mg) break;
    }
#undef STEP
#undef LOADI
    __syncthreads();   // ulist reused next group
  }

  D[2 * l] = D0;
  D[2 * l + 1] = D1;
}

// ---------------------------------------------------------------------------
// K5: parallel cluster assignment + segment atomics. cluster[j] = first head
// adjacent to j (head index provably <= j) -> scan only tiles k <= gy.
// Fused "first index at cluster-max y2" via ONE packed u64 atomicMax:
// (y2_bits << 32) | ~j  -- y2 >= 0 so uint order == float order; tie -> min j.
// ---------------------------------------------------------------------------
__global__ __launch_bounds__(256) void k_cluster(const u64* __restrict__ mtile,
                                                 const u64* __restrict__ D,
                                                 const float* __restrict__ ss,
                                                 const float* __restrict__ by2s,
                                                 int* __restrict__ cluster,
                                                 int* __restrict__ cnt,
                                                 float* __restrict__ prob,
                                                 u64* __restrict__ pk) {
  __shared__ u64 hlds[NT];
  __shared__ int red[4][64];
  int gy = blockIdx.x;
  if (threadIdx.x < NT) hlds[threadIdx.x] = D[threadIdx.x];
  __syncthreads();
  int w = threadIdx.x >> 6, r = threadIdx.x & 63;
  int best = 0x7fffffff;
  for (int k = w; k <= gy; k += 4) {      // per-group candidates ascend with k
    u64 v = mtile[((size_t)gy * NT + k) * 64 + r] & hlds[k];
    if (v) { best = k * 64 + __builtin_ctzll(v); break; }
  }
  red[w][r] = best;
  __syncthreads();
  if (w == 0) {
    int b = min(min(red[0][r], red[1][r]), min(red[2][r], red[3][r]));
    int j = gy * 64 + r;
    cluster[j] = b;
    atomicAdd(&cnt[b], 1);
    atomicAdd(&prob[b], ss[j]);
    atomicMax((unsigned long long*)&pk[b],
              ((u64)__float_as_uint(by2s[j]) << 32) | (u64)(0xFFFFFFFFu - (unsigned)j));
  }
}

// ---------------------------------------------------------------------------
// K6: outputs. out[j][0..4] then keep[j] appended (floats 0/1).
// first index recovered from packed atomicMax: ~low32(pk).
// ---------------------------------------------------------------------------
__global__ __launch_bounds__(256) void k_out(const int* __restrict__ cluster,
                                             const float* __restrict__ bx1s, const float* __restrict__ by1s,
                                             const float* __restrict__ bx2s, const float* __restrict__ by2s,
                                             const int* __restrict__ cnt,
                                             const float* __restrict__ prob,
                                             const u64* __restrict__ pk,
                                             const int* __restrict__ num_models,
                                             float* __restrict__ out) {
  int j = blockIdx.x * 256 + threadIdx.x;
  if (j >= N) return;
  int c = cluster[j];
  int nm = num_models[0];
  bool valid = (float)cnt[c] >= (float)nm / 3.0f;
  unsigned fj = 0xFFFFFFFFu - (unsigned)(pk[c] & 0xFFFFFFFFull);
  bool keep = (fj == (unsigned)j) && valid;
  float o0 = 0.f, o1 = 0.f, o2 = 0.f, o3 = 0.f, o4 = 0.f;
  if (keep) {
    o0 = bx1s[j]; o1 = by1s[j]; o2 = bx2s[j]; o3 = by2s[j];
    o4 = prob[c] / (float)nm;
  }
  out[j * 5 + 0] = o0;
  out[j * 5 + 1] = o1;
  out[j * 5 + 2] = o2;
  out[j * 5 + 3] = o3;
  out[j * 5 + 4] = o4;
  out[N * 5 + j] = keep ? 1.0f : 0.0f;
}

// ---------------------------------------------------------------------------
extern "C" void kernel_launch(void* const* d_in, const int* in_sizes, int n_in,
                              void* d_out, int out_size, void* d_ws, size_t ws_size,
                              hipStream_t stream) {
  const float* boxes = (const float*)d_in[0];
  const float* scores = (const float*)d_in[1];
  const int* num_models = (const int*)d_in[2];
  float* out = (float*)d_out;

  char* p = (char*)d_ws;
  auto take = [&](size_t bytes) {
    char* r = p;
    p += (bytes + 255) & ~(size_t)255;
    return r;
  };
  int* rankpart = (int*)take((size_t)8 * N * 4);
  float* bx1s = (float*)take((size_t)N * 4);
  float* by1s = (float*)take((size_t)N * 4);
  float* bx2s = (float*)take((size_t)N * 4);
  float* by2s = (float*)take((size_t)N * 4);
  float* ss   = (float*)take((size_t)N * 4);
  float* areas= (float*)take((size_t)N * 4);
  int* cluster= (int*)take((size_t)N * 4);
  int* cnt    = (int*)take((size_t)N * 4);
  float* prob = (float*)take((size_t)N * 4);
  u64* pk     = (u64*)take((size_t)N * 8);            // packed (y2max, ~first)
  u64* D      = (u64*)take((size_t)NT * 8);           // head bitmap
  u64* mtile  = (u64*)take((size_t)NT * NT * 64 * 8); // 8 MiB tiled adjacency
  u64* mrow   = (u64*)take((size_t)N * NT * 8);       // 8 MiB row-major adjacency

  k_rank<<<dim3(N / 256, 8), 256, 0, stream>>>(scores, rankpart);
  k_scatter<<<N / 256, 256, 0, stream>>>(boxes, scores, rankpart,
                                         bx1s, by1s, bx2s, by2s, ss, areas,
                                         cnt, prob, pk);
  k_adj<<<NT * (NT + 1) / 2, 64, 0, stream>>>(bx1s, by1s, bx2s, by2s, areas, mtile, mrow);
  k_sweep<<<1, 64, 0, stream>>>(mrow, D);
  k_cluster<<<NT, 256, 0, stream>>>(mtile, D, ss, by2s, cluster, cnt, prob, pk);
  k_out<<<N / 256, 256, 0, stream>>>(cluster, bx1s, by1s, bx2s, by2s, cnt, prob, pk, num_models, out);
}